// Round 8
// baseline (171.673 us; speedup 1.0000x reference)
//
#include <hip/hip_runtime.h>
#include <stdint.h>

#define NROWS 8192
#define DIM   2048
#define MARGIN 2.0f
#define SCALEQ (127.0f / 6.0f)          // quantize scale
#define S2     ((6.0f / 127.0f) * (6.0f / 127.0f))   // dequant^2

// ---- 256x256 i8 tile kernel geometry (byte units) ----
#define BT2     256
#define BKB     128                      // K-bytes (=elems) per tile-step
#define NKT     (DIM / BKB)              // 16 K-tiles
#define NT2     (NROWS / BT2)            // 32 tile-rows
#define NTILES2 (NT2 * (NT2 + 1) / 2)    // 528 upper-tri tiles
#define NQ      16                       // tiles 0..15 split into 4 row-quarters
#define ABUF_B  32768                    // A region bytes per buffer (256x128)
#define BUF_B   65536                    // A + B regions per buffer
#define HALF_B  16384                    // 128x128 half-tile bytes

typedef __attribute__((ext_vector_type(4)))  int  int4v;    // 16B operand
typedef __attribute__((ext_vector_type(16))) int  int16v;   // 32x32 i32 acc
typedef unsigned char uchar;

// triangular decode (ti <= tj)
__device__ __forceinline__ void decode_tile(int bid, int* ti, int* tj) {
    float fn = (float)NT2 + 0.5f;
    int r = (int)(fn - sqrtf(fn * fn - 2.0f * (float)bid));
    if (r < 0) r = 0;
    if (r >= NT2) r = NT2 - 1;
    while ((r + 1) * NT2 - ((r + 1) * r) / 2 <= bid) ++r;
    while (r * NT2 - (r * (r - 1)) / 2 > bid) --r;
    *ti = r;
    *tj = r + (bid - (r * NT2 - (r * (r - 1)) / 2));
}

__device__ __forceinline__ uint pack4(float4 v) {
    int q0 = (int)__builtin_rintf(v.x * SCALEQ);
    int q1 = (int)__builtin_rintf(v.y * SCALEQ);
    int q2 = (int)__builtin_rintf(v.z * SCALEQ);
    int q3 = (int)__builtin_rintf(v.w * SCALEQ);
    q0 = min(max(q0, -127), 127); q1 = min(max(q1, -127), 127);
    q2 = min(max(q2, -127), 127); q3 = min(max(q3, -127), 127);
    return (uint)(q0 & 0xFF) | ((uint)(q1 & 0xFF) << 8) |
           ((uint)(q2 & 0xFF) << 16) | ((uint)(q3 & 0xFF) << 24);
}

// ---------------- kernel 1: fp32 -> i8 quantize + fp32 row sum of squares ---
__global__ __launch_bounds__(256) void prep_kernel(const float* __restrict__ p,
                                                   uchar* __restrict__ pb,
                                                   float* __restrict__ sq) {
    int row = blockIdx.x;
    int t = threadIdx.x;
    const float4* prow = (const float4*)(p + (size_t)row * DIM);
    uint* qrow = (uint*)(pb + (size_t)row * DIM);
    float4 a = prow[t];
    float4 b = prow[t + 256];
    float s = a.x * a.x + a.y * a.y + a.z * a.z + a.w * a.w
            + b.x * b.x + b.y * b.y + b.z * b.z + b.w * b.w;
    qrow[t] = pack4(a);
    qrow[t + 256] = pack4(b);
#pragma unroll
    for (int o = 32; o > 0; o >>= 1) s += __shfl_down(s, o, 64);
    __shared__ float wsums[4];
    int lane = t & 63, wvv = t >> 6;
    if (lane == 0) wsums[wvv] = s;
    __syncthreads();
    if (t == 0) sq[row] = wsums[0] + wsums[1] + wsums[2] + wsums[3];
}

// ---------------- staging: global -> LDS, linear dest, pre-swizzled src -----
// 256 threads: 4 r-chunks of 32 rows each (4KB per chunk).
// which: 0 = A half0, 1 = A half1, 2 = B half0, 3 = B half1, for K-tile t.
// t >= NKT clamps to t-2 (parity preserved, dead data, same write window).
__device__ __forceinline__ void stage_ht(const uchar* __restrict__ pb,
                                         uchar* lds, int t, int which,
                                         int ibase, int jbase, int tid) {
    if (t >= NKT) t -= 2;
    const int h = which & 1;
    const int row0 = ((which >= 2) ? jbase : ibase) + h * 128;
    const uchar* g0 = pb + (size_t)row0 * DIM + t * BKB;
    uchar* l0 = lds + (t & 1) * BUF_B + ((which >= 2) ? ABUF_B : 0) + h * HALF_B;
#pragma unroll
    for (int r = 0; r < 4; ++r) {
        int row = r * 32 + (tid >> 3);
        int c8 = (tid & 7) ^ ((tid >> 3) & 7);         // pre-swizzled 16B slot
        const uchar* g = g0 + (size_t)row * DIM + c8 * 16;
        uchar* l = l0 + r * 4096 + (tid >> 6) * 1024;  // wave-uniform (+lane*16 HW)
        __builtin_amdgcn_global_load_lds(
            (const __attribute__((address_space(1))) uint32_t*)g,
            (__attribute__((address_space(3))) uint32_t*)l, 16, 0, 0);
    }
}

// quarter-block A stage: 64 rows only (2 chunks), into A region rows 0..63
__device__ __forceinline__ void stage_qA(const uchar* __restrict__ pb,
                                         uchar* lds, int t, int ibase, int tid) {
    if (t >= NKT) t -= 2;
    const uchar* g0 = pb + (size_t)ibase * DIM + t * BKB;
    uchar* l0 = lds + (t & 1) * BUF_B;
#pragma unroll
    for (int r = 0; r < 2; ++r) {
        int row = r * 32 + (tid >> 3);
        int c8 = (tid & 7) ^ ((tid >> 3) & 7);
        const uchar* g = g0 + (size_t)row * DIM + c8 * 16;
        uchar* l = l0 + r * 4096 + (tid >> 6) * 1024;
        __builtin_amdgcn_global_load_lds(
            (const __attribute__((address_space(1))) uint32_t*)g,
            (__attribute__((address_space(3))) uint32_t*)l, 16, 0, 0);
    }
}

#define BARF()    do { __builtin_amdgcn_s_barrier(); \
                       asm volatile("" ::: "memory"); } while (0)
#define WAITL()   asm volatile("s_waitcnt lgkmcnt(0)" ::: "memory")
#define WAITV16() asm volatile("s_waitcnt vmcnt(16)" ::: "memory")
#define WAITV10() asm volatile("s_waitcnt vmcnt(10)" ::: "memory")
#define WAITV0()  asm volatile("s_waitcnt vmcnt(0)" ::: "memory")

// swizzled ds_read of 16B i8 frags: row stride 128B, slot ^= (row&7) = (lane&7)
// A half MH: rows wr2*128 + (MH*2+mt)*32 + (lane&31); 8 reads -> DST[2][4]
#define RD_A(DST, MH)                                                          \
    _Pragma("unroll") for (int mt = 0; mt < 2; ++mt)                           \
    _Pragma("unroll") for (int s = 0; s < 4; ++s) {                            \
        int rl = wr2 * 128 + ((MH) * 2 + mt) * 32 + (lane & 31);               \
        DST[mt][s] = *(const int4v*)&Ab[rl * 128 +                             \
                      (((2 * s + kh) ^ (lane & 7)) * 16)];                     \
    }

#define RD_B(DST, NH)                                                          \
    _Pragma("unroll") for (int nt = 0; nt < 2; ++nt)                           \
    _Pragma("unroll") for (int s = 0; s < 4; ++s) {                            \
        int rl = wc2 * 128 + ((NH) * 2 + nt) * 32 + (lane & 31);               \
        DST[nt][s] = *(const int4v*)&Bb[rl * 128 +                             \
                      (((2 * s + kh) ^ (lane & 7)) * 16)];                     \
    }

#define MM(AF, BF, MH, NH)                                                     \
    _Pragma("unroll") for (int mt = 0; mt < 2; ++mt)                           \
    _Pragma("unroll") for (int nt = 0; nt < 2; ++nt)                           \
    _Pragma("unroll") for (int s = 0; s < 4; ++s)                              \
        acc[(MH) * 2 + mt][(NH) * 2 + nt] =                                    \
            __builtin_amdgcn_mfma_i32_32x32x32_i8(                             \
                AF[mt][s], BF[nt][s], acc[(MH) * 2 + mt][(NH) * 2 + nt],       \
                0, 0, 0);

// FULL step (1 wave/SIMD, 128x128/wave). Reads issued ahead of consuming
// cluster; compiler's counted lgkmcnt gates each MFMA quadrant while LDS
// service hides under the matrix-pipe shadow. One stage window per step.
#define STEP_FULL(T, BUF)                                                      \
    {                                                                          \
        const uchar* Ab = &lds[(BUF) * BUF_B];                                 \
        const uchar* Bb = &lds[(BUF) * BUF_B + ABUF_B];                        \
        RD_A(af0, 0); RD_B(bf0, 0);                                            \
        RD_A(af1, 1);                                                          \
        MM(af0, bf0, 0, 0);                                                    \
        RD_B(bf1, 1);                                                          \
        MM(af1, bf0, 1, 0);                                                    \
        RD_A(af0, 0);            /* re-read A01 (caps live frag sets at 3) */  \
        MM(af1, bf1, 1, 1);                                                    \
        MM(af0, bf1, 0, 1);                                                    \
        WAITL(); BARF();                                                       \
        stage_ht(pb, lds, (T) + 2, 2, ibase, jbase, tid);                      \
        stage_ht(pb, lds, (T) + 2, 3, ibase, jbase, tid);                      \
        stage_ht(pb, lds, (T) + 2, 0, ibase, jbase, tid);                      \
        stage_ht(pb, lds, (T) + 2, 1, ibase, jbase, tid);                      \
        WAITV16(); BARF();                                                     \
    }

// QUARTER step (64x256 strip; wave w owns cols w*64..w*64+63)
#define STEP_Q(T, BUF)                                                         \
    {                                                                          \
        const uchar* Ab = &lds[(BUF) * BUF_B];                                 \
        const uchar* Bb = &lds[(BUF) * BUF_B + ABUF_B];                        \
        _Pragma("unroll") for (int mt = 0; mt < 2; ++mt)                       \
        _Pragma("unroll") for (int s = 0; s < 4; ++s) {                        \
            int rl = mt * 32 + (lane & 31);                                    \
            aq[mt][s] = *(const int4v*)&Ab[rl * 128 +                          \
                         (((2 * s + kh) ^ (lane & 7)) * 16)];                  \
        }                                                                      \
        _Pragma("unroll") for (int nt = 0; nt < 2; ++nt)                       \
        _Pragma("unroll") for (int s = 0; s < 4; ++s) {                        \
            int rl = wv * 64 + nt * 32 + (lane & 31);                          \
            bq[nt][s] = *(const int4v*)&Bb[rl * 128 +                          \
                         (((2 * s + kh) ^ (lane & 7)) * 16)];                  \
        }                                                                      \
        _Pragma("unroll") for (int mt = 0; mt < 2; ++mt)                       \
        _Pragma("unroll") for (int nt = 0; nt < 2; ++nt)                       \
        _Pragma("unroll") for (int s = 0; s < 4; ++s)                          \
            accq[mt][nt] = __builtin_amdgcn_mfma_i32_32x32x32_i8(              \
                aq[mt][s], bq[nt][s], accq[mt][nt], 0, 0, 0);                  \
        WAITL(); BARF();                                                       \
        stage_qA(pb, lds, (T) + 2, ibase, tid);                                \
        stage_ht(pb, lds, (T) + 2, 2, ibase, jbase, tid);                      \
        stage_ht(pb, lds, (T) + 2, 3, ibase, jbase, tid);                      \
        WAITV10(); BARF();                                                     \
    }

// ---------------- kernel 2: triangular Gram + fused loss --------------------
// Grid = 64 quarter blocks (tiles 0..15 x 4 row-quarters, dispatched first)
//      + 512 full tiles. 256 threads, 4 waves, 1 wave/SIMD.
__global__ __launch_bounds__(256, 1) void tile2_kernel(
    const uchar* __restrict__ pb, const float* __restrict__ sq,
    const int* __restrict__ gt, double* __restrict__ accum) {

    __shared__ uchar lds[2 * BUF_B];   // 128 KiB
    __shared__ float wsum[4];

    const int bx = (int)blockIdx.x;
    const bool is_q = (bx < 4 * NQ);
    int bid, qq = 0;
    if (is_q) { bid = bx >> 2; qq = bx & 3; }
    else { int f = bx - 4 * NQ; bid = NQ + ((f & 7) << 6) + (f >> 3); } // 512=8*64

    int ti, tj;
    decode_tile(bid, &ti, &tj);

    const int tid = threadIdx.x;
    const int lane = tid & 63;
    const int kh = lane >> 5;            // K-half within a 32-wide slice
    const int wv = tid >> 6;             // wave 0..3
    const int wr2 = wv >> 1;             // full: row half (128 rows)
    const int wc2 = wv & 1;              // full: col half (128 cols)
    const int jbase = tj * BT2;
    const int ibase = ti * BT2 + (is_q ? qq * 64 : 0);

    const float invd = 1.0f / (float)DIM;
    float lsum = 0.f;

    if (!is_q) {
        int16v acc[4][4] = {};
        int4v af0[2][4], af1[2][4], bf0[2][4], bf1[2][4];

        // prologue: tiles 0,1 fully issued (32); vmcnt(16) -> tile0 resident.
        stage_ht(pb, lds, 0, 2, ibase, jbase, tid);
        stage_ht(pb, lds, 0, 3, ibase, jbase, tid);
        stage_ht(pb, lds, 0, 0, ibase, jbase, tid);
        stage_ht(pb, lds, 0, 1, ibase, jbase, tid);
        stage_ht(pb, lds, 1, 2, ibase, jbase, tid);
        stage_ht(pb, lds, 1, 3, ibase, jbase, tid);
        stage_ht(pb, lds, 1, 0, ibase, jbase, tid);
        stage_ht(pb, lds, 1, 1, ibase, jbase, tid);
        WAITV16();
        BARF();

#pragma unroll 1
        for (int s0 = 0; s0 < NKT; s0 += 2) {
            STEP_FULL(s0, 0);
            STEP_FULL(s0 + 1, 1);
        }
        WAITV0();
        BARF();

        // fused epilogue
        int j0 = jbase + wc2 * 128 + (lane & 31);
        float sqj[4]; int gj[4];
#pragma unroll
        for (int nh = 0; nh < 4; ++nh) { int j = j0 + nh * 32; sqj[nh] = sq[j]; gj[nh] = gt[j]; }
        const float wb = (ti != tj) ? 2.0f : 1.0f;
#pragma unroll
        for (int mi = 0; mi < 4; ++mi) {
#pragma unroll
            for (int q = 0; q < 4; ++q) {
#pragma unroll
                for (int rr = 0; rr < 4; ++rr) {
                    int i = ibase + wr2 * 128 + mi * 32 + rr + 8 * q + 4 * kh;
                    float sqi = sq[i];
                    int gi = gt[i];
#pragma unroll
                    for (int nh = 0; nh < 4; ++nh) {
                        int j = j0 + nh * 32;
                        float dot = S2 * (float)acc[mi][nh][q * 4 + rr];
                        float d2 = fmaxf(sqi + sqj[nh] - 2.0f * dot, 0.0f) * invd;
                        float term = (gi == gj[nh]) ? d2 : fmaxf(MARGIN - d2, 0.0f);
                        float w = wb;
                        if (ti == tj && i == j) w = 2.0f;
                        lsum += w * term;
                    }
                }
            }
        }
    } else {
        int16v accq[2][2] = {};
        int4v aq[2][4], bq[2][4];

        // prologue: tiles 0,1 (10 each); vmcnt(10) -> tile0 resident.
        stage_qA(pb, lds, 0, ibase, tid);
        stage_ht(pb, lds, 0, 2, ibase, jbase, tid);
        stage_ht(pb, lds, 0, 3, ibase, jbase, tid);
        stage_qA(pb, lds, 1, ibase, tid);
        stage_ht(pb, lds, 1, 2, ibase, jbase, tid);
        stage_ht(pb, lds, 1, 3, ibase, jbase, tid);
        WAITV10();
        BARF();

#pragma unroll 1
        for (int s0 = 0; s0 < NKT; s0 += 2) {
            STEP_Q(s0, 0);
            STEP_Q(s0 + 1, 1);
        }
        WAITV0();
        BARF();

        int j0 = jbase + wv * 64 + (lane & 31);
        float sqj[2]; int gj[2];
#pragma unroll
        for (int nt = 0; nt < 2; ++nt) { int j = j0 + nt * 32; sqj[nt] = sq[j]; gj[nt] = gt[j]; }
        const float wb = (ti != tj) ? 2.0f : 1.0f;
#pragma unroll
        for (int mt = 0; mt < 2; ++mt) {
#pragma unroll
            for (int q = 0; q < 4; ++q) {
#pragma unroll
                for (int rr = 0; rr < 4; ++rr) {
                    int i = ibase + mt * 32 + rr + 8 * q + 4 * kh;
                    float sqi = sq[i];
                    int gi = gt[i];
#pragma unroll
                    for (int nt = 0; nt < 2; ++nt) {
                        int j = j0 + nt * 32;
                        float dot = S2 * (float)accq[mt][nt][q * 4 + rr];
                        float d2 = fmaxf(sqi + sqj[nt] - 2.0f * dot, 0.0f) * invd;
                        float term = (gi == gj[nt]) ? d2 : fmaxf(MARGIN - d2, 0.0f);
                        float w = wb;
                        if (ti == tj && i == j) w = 2.0f;
                        lsum += w * term;
                    }
                }
            }
        }
    }

#pragma unroll
    for (int o = 32; o > 0; o >>= 1) lsum += __shfl_down(lsum, o, 64);
    if (lane == 0) wsum[wv] = lsum;
    __syncthreads();
    if (tid == 0)
        atomicAdd(accum, (double)(wsum[0] + wsum[1] + wsum[2] + wsum[3]));
}

// ---------------- kernel 3: finalize ----------------------------------------
__global__ void finalize_kernel(const double* __restrict__ accum,
                                float* __restrict__ out) {
    if (threadIdx.x == 0)
        out[0] = (float)(accum[0] * (1.0 / ((double)NROWS * (double)(NROWS - 1))));
}

extern "C" void kernel_launch(void* const* d_in, const int* in_sizes, int n_in,
                              void* d_out, int out_size, void* d_ws, size_t ws_size,
                              hipStream_t stream) {
    (void)in_sizes; (void)n_in; (void)out_size; (void)ws_size;
    const float* p = (const float*)d_in[0];
    const int* gt = (const int*)d_in[1];
    float* out = (float*)d_out;

    // ws layout: pb 16MB i8 | sq 32KB | accum 8B
    uchar* pb = (uchar*)d_ws;
    size_t off = (size_t)NROWS * DIM;                   // 16,777,216
    float* sq = (float*)((char*)d_ws + off);
    off += (size_t)NROWS * sizeof(float);               // +32 KB
    double* accum = (double*)((char*)d_ws + off);

    (void)hipMemsetAsync(accum, 0, sizeof(double), stream);
    prep_kernel<<<NROWS, 256, 0, stream>>>(p, pb, sq);
    tile2_kernel<<<4 * NQ + 512, 256, 0, stream>>>(pb, sq, gt, accum);
    finalize_kernel<<<1, 64, 0, stream>>>(accum, out);
}

// Round 9
// 112.704 us; speedup vs baseline: 1.5232x; 1.5232x over previous
//
#include <hip/hip_runtime.h>
#include <stdint.h>

#define NROWS 8192
#define DIM   2048
#define MARGIN 2.0f
#define SCALEQ (127.0f / 6.0f)          // quantize scale
#define S2     ((6.0f / 127.0f) * (6.0f / 127.0f))   // dequant^2

// ---- 256x256 i8 tile kernel geometry (byte units) ----
#define BT2     256
#define BKB     128                      // K-bytes (=elems) per tile-step
#define NKT     (DIM / BKB)              // 16 K-tiles
#define NT2     (NROWS / BT2)            // 32 tile-rows
#define NTILES2 (NT2 * (NT2 + 1) / 2)    // 528 upper-tri tiles
#define NQ      16                       // tiles 0..15 split into 4 row-quarters
#define ABUF_B  32768                    // A region bytes per buffer (256x128)
#define BUF_B   65536                    // A + B regions per buffer
#define HALF_B  16384                    // 128x128 half-tile bytes

typedef __attribute__((ext_vector_type(4)))  int  int4v;    // 16B operand
typedef __attribute__((ext_vector_type(16))) int  int16v;   // 32x32 i32 acc
typedef unsigned char uchar;

// triangular decode (ti <= tj)
__device__ __forceinline__ void decode_tile(int bid, int* ti, int* tj) {
    float fn = (float)NT2 + 0.5f;
    int r = (int)(fn - sqrtf(fn * fn - 2.0f * (float)bid));
    if (r < 0) r = 0;
    if (r >= NT2) r = NT2 - 1;
    while ((r + 1) * NT2 - ((r + 1) * r) / 2 <= bid) ++r;
    while (r * NT2 - (r * (r - 1)) / 2 > bid) --r;
    *ti = r;
    *tj = r + (bid - (r * NT2 - (r * (r - 1)) / 2));
}

__device__ __forceinline__ uint pack4(float4 v) {
    int q0 = (int)__builtin_rintf(v.x * SCALEQ);
    int q1 = (int)__builtin_rintf(v.y * SCALEQ);
    int q2 = (int)__builtin_rintf(v.z * SCALEQ);
    int q3 = (int)__builtin_rintf(v.w * SCALEQ);
    q0 = min(max(q0, -127), 127); q1 = min(max(q1, -127), 127);
    q2 = min(max(q2, -127), 127); q3 = min(max(q3, -127), 127);
    return (uint)(q0 & 0xFF) | ((uint)(q1 & 0xFF) << 8) |
           ((uint)(q2 & 0xFF) << 16) | ((uint)(q3 & 0xFF) << 24);
}

// ---------------- kernel 1: fp32 -> i8 quantize + fp32 row sum of squares ---
__global__ __launch_bounds__(256) void prep_kernel(const float* __restrict__ p,
                                                   uchar* __restrict__ pb,
                                                   float* __restrict__ sq) {
    int row = blockIdx.x;
    int t = threadIdx.x;
    const float4* prow = (const float4*)(p + (size_t)row * DIM);
    uint* qrow = (uint*)(pb + (size_t)row * DIM);
    float4 a = prow[t];
    float4 b = prow[t + 256];
    float s = a.x * a.x + a.y * a.y + a.z * a.z + a.w * a.w
            + b.x * b.x + b.y * b.y + b.z * b.z + b.w * b.w;
    qrow[t] = pack4(a);
    qrow[t + 256] = pack4(b);
#pragma unroll
    for (int o = 32; o > 0; o >>= 1) s += __shfl_down(s, o, 64);
    __shared__ float wsums[4];
    int lane = t & 63, wvv = t >> 6;
    if (lane == 0) wsums[wvv] = s;
    __syncthreads();
    if (t == 0) sq[row] = wsums[0] + wsums[1] + wsums[2] + wsums[3];
}

// ---------------- staging: global -> LDS, linear dest, pre-swizzled src -----
// 512 threads, half-tile = 128 rows x 128B = 16KB -> 2 insts/thread.
// which: 0 = A half0, 1 = A half1, 2 = B half0, 3 = B half1, for K-tile t.
// t >= NKT clamps to t-2 (parity preserved, dead data, same write window).
__device__ __forceinline__ void stage_ht(const uchar* __restrict__ pb,
                                         uchar* lds, int t, int which,
                                         int ibase, int jbase, int tid) {
    if (t >= NKT) t -= 2;
    const int h = which & 1;
    const int row0 = ((which >= 2) ? jbase : ibase) + h * 128;
    const uchar* g0 = pb + (size_t)row0 * DIM + t * BKB;
    uchar* l0 = lds + (t & 1) * BUF_B + ((which >= 2) ? ABUF_B : 0) + h * HALF_B;
#pragma unroll
    for (int r = 0; r < 2; ++r) {
        int row = r * 64 + (tid >> 3);
        int c8 = (tid & 7) ^ ((tid >> 3) & 7);         // pre-swizzled 16B slot
        const uchar* g = g0 + (size_t)row * DIM + c8 * 16;
        uchar* l = l0 + r * 8192 + (tid >> 6) * 1024;  // wave-uniform (+lane*16 HW)
        __builtin_amdgcn_global_load_lds(
            (const __attribute__((address_space(1))) uint32_t*)g,
            (__attribute__((address_space(3))) uint32_t*)l, 16, 0, 0);
    }
}

// quarter-block A stage: 64 rows x 128B = 8KB -> 1 inst/thread (512 threads)
__device__ __forceinline__ void stage_qA(const uchar* __restrict__ pb,
                                         uchar* lds, int t, int ibase, int tid) {
    if (t >= NKT) t -= 2;
    const uchar* g0 = pb + (size_t)ibase * DIM + t * BKB;
    uchar* l0 = lds + (t & 1) * BUF_B;
    int row = tid >> 3;                                // 0..63
    int c8 = (tid & 7) ^ ((tid >> 3) & 7);
    const uchar* g = g0 + (size_t)row * DIM + c8 * 16;
    uchar* l = l0 + (tid >> 6) * 1024;
    __builtin_amdgcn_global_load_lds(
        (const __attribute__((address_space(1))) uint32_t*)g,
        (__attribute__((address_space(3))) uint32_t*)l, 16, 0, 0);
}

#define BARF()   do { __builtin_amdgcn_s_barrier(); \
                      asm volatile("" ::: "memory"); } while (0)
#define WLG4()   asm volatile("s_waitcnt lgkmcnt(4)" ::: "memory")
#define WLG0()   asm volatile("s_waitcnt lgkmcnt(0)" ::: "memory")
#define WAITV8() asm volatile("s_waitcnt vmcnt(8)" ::: "memory")
#define WAITV5() asm volatile("s_waitcnt vmcnt(5)" ::: "memory")
#define WAITV0() asm volatile("s_waitcnt vmcnt(0)" ::: "memory")
#define PRIO1()  __builtin_amdgcn_s_setprio(1)
#define PRIO0()  __builtin_amdgcn_s_setprio(0)
#define SB0()    __builtin_amdgcn_sched_barrier(0)

// swizzled ds_read of 16B i8 frags: row stride 128B, slot ^= (lane&7)
#define RD_A(DST, MH)                                                          \
    _Pragma("unroll") for (int mt = 0; mt < 2; ++mt)                           \
    _Pragma("unroll") for (int s = 0; s < 4; ++s) {                            \
        int rl = wr * 128 + ((MH) * 2 + mt) * 32 + (lane & 31);                \
        DST[mt][s] = *(const int4v*)&Ab[rl * 128 +                             \
                      (((2 * s + kh) ^ (lane & 7)) * 16)];                     \
    }

#define RD_B(DST, NH)                                                          \
    _Pragma("unroll") for (int s = 0; s < 4; ++s) {                            \
        int rl = wc * 64 + (NH) * 32 + (lane & 31);                            \
        DST[s] = *(const int4v*)&Bb[rl * 128 +                                 \
                  (((2 * s + kh) ^ (lane & 7)) * 16)];                         \
    }

// s-outer MFMA (dependency spacing 2 instead of chains of 4)
#define MFMA_QR(AF, BF, MH, NH, S0, S1)                                        \
    _Pragma("unroll") for (int s = (S0); s < (S1); ++s)                        \
    _Pragma("unroll") for (int mt = 0; mt < 2; ++mt)                           \
        acc[(MH) * 2 + mt][NH] = __builtin_amdgcn_mfma_i32_32x32x32_i8(        \
            AF[mt][s], BF[s], acc[(MH) * 2 + mt][NH], 0, 0, 0);

// FULL step: read-ahead + counted lgkm + 3 barriers.
//   issue A0,B0 | B1; lgkm(4) -> Q00 runs while B1 lands;
//   Q01 first half; A1 reads interleave; Q01 second half;
//   BAR; stage B(T+2); lgkm(0) -> Q10; BAR; stage A(T+2); Q11; WAITV8; BAR.
#define STEP_FULL(T, BUF)                                                      \
    {                                                                          \
        const uchar* Ab = &lds[(BUF) * BUF_B];                                 \
        const uchar* Bb = &lds[(BUF) * BUF_B + ABUF_B];                        \
        RD_A(af0, 0); RD_B(bf0, 0);                                            \
        SB0();                                                                 \
        RD_B(bf1, 1);                                                          \
        WLG4(); SB0();                                                         \
        PRIO1(); MFMA_QR(af0, bf0, 0, 0, 0, 4); PRIO0();                       \
        WLG0(); SB0();                                                         \
        PRIO1(); MFMA_QR(af0, bf1, 0, 1, 0, 2); PRIO0();                       \
        SB0();                                                                 \
        RD_A(af1, 1);                                                          \
        PRIO1(); MFMA_QR(af0, bf1, 0, 1, 2, 4); PRIO0();                       \
        BARF();                                                                \
        stage_ht(pb, lds, (T) + 2, 2, ibase, jbase, tid);                      \
        stage_ht(pb, lds, (T) + 2, 3, ibase, jbase, tid);                      \
        WLG0(); SB0();                                                         \
        PRIO1(); MFMA_QR(af1, bf0, 1, 0, 0, 4); PRIO0();                       \
        BARF();                                                                \
        stage_ht(pb, lds, (T) + 2, 0, ibase, jbase, tid);                      \
        stage_ht(pb, lds, (T) + 2, 1, ibase, jbase, tid);                      \
        PRIO1(); MFMA_QR(af1, bf1, 1, 1, 0, 4); PRIO0();                       \
        WAITV8(); BARF();                                                      \
    }

// QUARTER step (64x256 strip; 8 waves, wave w owns cols w*32..w*32+31)
#define STEP_Q(T, BUF)                                                         \
    {                                                                          \
        const uchar* Ab = &lds[(BUF) * BUF_B];                                 \
        const uchar* Bb = &lds[(BUF) * BUF_B + ABUF_B];                        \
        _Pragma("unroll") for (int mt = 0; mt < 2; ++mt)                       \
        _Pragma("unroll") for (int s = 0; s < 4; ++s) {                        \
            int rl = mt * 32 + (lane & 31);                                    \
            aq[mt][s] = *(const int4v*)&Ab[rl * 128 +                          \
                         (((2 * s + kh) ^ (lane & 7)) * 16)];                  \
        }                                                                      \
        _Pragma("unroll") for (int s = 0; s < 4; ++s) {                        \
            int rl = wv * 32 + (lane & 31);                                    \
            bq[s] = *(const int4v*)&Bb[rl * 128 +                              \
                     (((2 * s + kh) ^ (lane & 7)) * 16)];                      \
        }                                                                      \
        WLG0(); SB0();                                                         \
        PRIO1();                                                               \
        _Pragma("unroll") for (int s = 0; s < 4; ++s)                          \
        _Pragma("unroll") for (int mt = 0; mt < 2; ++mt)                       \
            accq[mt] = __builtin_amdgcn_mfma_i32_32x32x32_i8(                  \
                aq[mt][s], bq[s], accq[mt], 0, 0, 0);                          \
        PRIO0();                                                               \
        BARF();                                                                \
        stage_qA(pb, lds, (T) + 2, ibase, tid);                                \
        stage_ht(pb, lds, (T) + 2, 2, ibase, jbase, tid);                      \
        stage_ht(pb, lds, (T) + 2, 3, ibase, jbase, tid);                      \
        WAITV5(); BARF();                                                      \
    }

// ---------------- kernel 2: triangular Gram + fused loss --------------------
// Grid = 64 quarter blocks (tiles 0..15 x 4 row-quarters, first) + 512 fulls.
// 512 threads, 8 waves (2 waves/SIMD).
__global__ __launch_bounds__(512) void tile2_kernel(
    const uchar* __restrict__ pb, const float* __restrict__ sq,
    const int* __restrict__ gt, double* __restrict__ accum) {

    __shared__ uchar lds[2 * BUF_B];   // 128 KiB
    __shared__ float wsum[8];

    const int bx = (int)blockIdx.x;
    const bool is_q = (bx < 4 * NQ);
    int bid, qq = 0;
    if (is_q) { bid = bx >> 2; qq = bx & 3; }
    else { int f = bx - 4 * NQ; bid = NQ + ((f & 7) << 6) + (f >> 3); } // 512=8*64

    int ti, tj;
    decode_tile(bid, &ti, &tj);

    const int tid = threadIdx.x;
    const int lane = tid & 63;
    const int kh = lane >> 5;            // K-half within a 32-wide slice
    const int wv = tid >> 6;             // wave 0..7
    const int wr = wv >> 2;              // full: row half (128 rows)
    const int wc = wv & 3;               // full: col group (64 cols)
    const int jbase = tj * BT2;
    const int ibase = ti * BT2 + (is_q ? qq * 64 : 0);

    const float invd = 1.0f / (float)DIM;
    float lsum = 0.f;

    if (!is_q) {
        int16v acc[4][2] = {};
        int4v af0[2][4], af1[2][4];
        int4v bf0[4], bf1[4];

        // prologue: tiles 0,1 fully issued (16 insts); vmcnt(8) -> tile0 resident.
        stage_ht(pb, lds, 0, 2, ibase, jbase, tid);
        stage_ht(pb, lds, 0, 3, ibase, jbase, tid);
        stage_ht(pb, lds, 0, 0, ibase, jbase, tid);
        stage_ht(pb, lds, 0, 1, ibase, jbase, tid);
        stage_ht(pb, lds, 1, 2, ibase, jbase, tid);
        stage_ht(pb, lds, 1, 3, ibase, jbase, tid);
        stage_ht(pb, lds, 1, 0, ibase, jbase, tid);
        stage_ht(pb, lds, 1, 1, ibase, jbase, tid);
        WAITV8();
        BARF();

#pragma unroll 1
        for (int s0 = 0; s0 < NKT; s0 += 2) {
            STEP_FULL(s0, 0);
            STEP_FULL(s0 + 1, 1);
        }
        WAITV0();
        BARF();

        // fused epilogue: dequant -> d2 -> contrastive term -> weighted sum
        int j0 = jbase + wc * 64 + (lane & 31);
        float sqj[2]; int gj[2];
#pragma unroll
        for (int n = 0; n < 2; ++n) { int j = j0 + n * 32; sqj[n] = sq[j]; gj[n] = gt[j]; }
        const float wb = (ti != tj) ? 2.0f : 1.0f;
#pragma unroll
        for (int mi = 0; mi < 4; ++mi) {
#pragma unroll
            for (int q = 0; q < 4; ++q) {
#pragma unroll
                for (int rr = 0; rr < 4; ++rr) {
                    int i = ibase + wr * 128 + mi * 32 + rr + 8 * q + 4 * kh;
                    float sqi = sq[i];
                    int gi = gt[i];
#pragma unroll
                    for (int n = 0; n < 2; ++n) {
                        int j = j0 + n * 32;
                        float dot = S2 * (float)acc[mi][n][q * 4 + rr];
                        float d2 = fmaxf(sqi + sqj[n] - 2.0f * dot, 0.0f) * invd;
                        float term = (gi == gj[n]) ? d2 : fmaxf(MARGIN - d2, 0.0f);
                        float w = wb;
                        if (ti == tj && i == j) w = 2.0f;
                        lsum += w * term;
                    }
                }
            }
        }
    } else {
        int16v accq[2] = {};
        int4v aq[2][4], bq[4];

        // prologue: tiles 0,1 (5 insts each); vmcnt(5) -> tile0 resident.
        stage_qA(pb, lds, 0, ibase, tid);
        stage_ht(pb, lds, 0, 2, ibase, jbase, tid);
        stage_ht(pb, lds, 0, 3, ibase, jbase, tid);
        stage_qA(pb, lds, 1, ibase, tid);
        stage_ht(pb, lds, 1, 2, ibase, jbase, tid);
        stage_ht(pb, lds, 1, 3, ibase, jbase, tid);
        WAITV5();
        BARF();

#pragma unroll 1
        for (int s0 = 0; s0 < NKT; s0 += 2) {
            STEP_Q(s0, 0);
            STEP_Q(s0 + 1, 1);
        }
        WAITV0();
        BARF();

        int j = jbase + wv * 32 + (lane & 31);
        float sqj = sq[j];
        int gj = gt[j];
        const float wb = (ti != tj) ? 2.0f : 1.0f;
#pragma unroll
        for (int mt = 0; mt < 2; ++mt) {
#pragma unroll
            for (int q = 0; q < 4; ++q) {
#pragma unroll
                for (int rr = 0; rr < 4; ++rr) {
                    int i = ibase + mt * 32 + rr + 8 * q + 4 * kh;
                    float dot = S2 * (float)accq[mt][q * 4 + rr];
                    float d2 = fmaxf(sq[i] + sqj - 2.0f * dot, 0.0f) * invd;
                    float term = (gt[i] == gj) ? d2 : fmaxf(MARGIN - d2, 0.0f);
                    float w = wb;
                    if (ti == tj && i == j) w = 2.0f;
                    lsum += w * term;
                }
            }
        }
    }

#pragma unroll
    for (int o = 32; o > 0; o >>= 1) lsum += __shfl_down(lsum, o, 64);
    if (lane == 0) wsum[wv] = lsum;
    __syncthreads();
    if (tid == 0) {
        float s = 0.f;
#pragma unroll
        for (int w = 0; w < 8; ++w) s += wsum[w];
        atomicAdd(accum, (double)s);
    }
}

// ---------------- kernel 3: finalize ----------------------------------------
__global__ void finalize_kernel(const double* __restrict__ accum,
                                float* __restrict__ out) {
    if (threadIdx.x == 0)
        out[0] = (float)(accum[0] * (1.0 / ((double)NROWS * (double)(NROWS - 1))));
}

extern "C" void kernel_launch(void* const* d_in, const int* in_sizes, int n_in,
                              void* d_out, int out_size, void* d_ws, size_t ws_size,
                              hipStream_t stream) {
    (void)in_sizes; (void)n_in; (void)out_size; (void)ws_size;
    const float* p = (const float*)d_in[0];
    const int* gt = (const int*)d_in[1];
    float* out = (float*)d_out;

    // ws layout: pb 16MB i8 | sq 32KB | accum 8B
    uchar* pb = (uchar*)d_ws;
    size_t off = (size_t)NROWS * DIM;                   // 16,777,216
    float* sq = (float*)((char*)d_ws + off);
    off += (size_t)NROWS * sizeof(float);               // +32 KB
    double* accum = (double*)((char*)d_ws + off);

    (void)hipMemsetAsync(accum, 0, sizeof(double), stream);
    prep_kernel<<<NROWS, 256, 0, stream>>>(p, pb, sq);
    tile2_kernel<<<4 * NQ + 512, 512, 0, stream>>>(pb, sq, gt, accum);
    finalize_kernel<<<1, 64, 0, stream>>>(accum, out);
}